// Round 8
// baseline (153.360 us; speedup 1.0000x reference)
//
#include <hip/hip_runtime.h>
#include <stdint.h>

#define TPB 256
#define ROWS_PB 256
#define KR 8
#define CS 16
#define IDXM 0x1FFFu

typedef unsigned long long u64;
typedef unsigned int u32;

__device__ __forceinline__ float waveReduceSum(float v){
#pragma unroll
  for (int o = 32; o > 0; o >>= 1) v += __shfl_down(v, o, 64);
  return v;
}

__device__ __forceinline__ u32 aload_u32(u32* p){
  return __hip_atomic_load(p, __ATOMIC_ACQUIRE, __HIP_MEMORY_SCOPE_AGENT);
}
__device__ __forceinline__ float aload_f32(float* p){
  return __hip_atomic_load(p, __ATOMIC_ACQUIRE, __HIP_MEMORY_SCOPE_AGENT);
}

// Fused single-pass chamfer/color: each (row,col) distance computed ONCE,
// feeding BOTH the row-min (s2f + argmin, gts side) and col-min (f2s, preds
// side), and likewise for colors. Lane grid 8x8: ri=lane&7 picks the row
// group (8 rows/thread, fixed -> row-min in registers), ci=lane>>3 picks the
// col pair per j-step. Col data read directly from global (L1 broadcast, no
// LDS staging, no main-loop barriers). Row pt-min is mantissa-packed
// (dist&~0x1FFF)|colidx so v_min3 tracks argmin; value noise <= dist*2^-10,
// color mins exact. Col mins: in-reg fold -> 3x shfl_xor(ri) -> LDS
// accumulate -> one global atomicMin flush per block.
__global__ void __launch_bounds__(TPB) pass_kernel(
    const float* __restrict__ gts, const float* __restrict__ preds,
    u32* __restrict__ packS2F, u32* __restrict__ distF2S,
    u32* __restrict__ colMin2, u32* __restrict__ colMin1,
    int N, int cpc)
{
  __shared__ u32 cminP[512];
  __shared__ u32 cminC[512];

  const int b = blockIdx.y;
  const int rb = blockIdx.x / CS;
  const int chunk = blockIdx.x - rb * CS;
  const int t = threadIdx.x;
  const int lane = t & 63, w = t >> 6;
  const int ri = lane & 7, ci = lane >> 3;
  const int rowBase = rb * ROWS_PB + w * 64 + ri * KR;
  const int colBase = chunk * cpc;

  for (int i = t; i < cpc; i += TPB){ cminP[i] = ~0u; cminC[i] = ~0u; }

  float ax[KR], ay[KR], az[KR], rx[KR];
  float cr[KR], cg_[KR], cb_[KR], rc[KR];
  float bD[KR], bC[KR];
#pragma unroll
  for (int k = 0; k < KR; k++){
    const float* p = gts + ((size_t)b * N + rowBase + k) * 6;
    float p0 = p[0], p1 = p[1], p2 = p[2], p3 = p[3], p4 = p[4], p5 = p[5];
    ax[k] = -2.f * p0; ay[k] = -2.f * p1; az[k] = -2.f * p2;
    rx[k] = fmaf(p0, p0, fmaf(p1, p1, p2 * p2));
    cr[k] = -2.f * p3; cg_[k] = -2.f * p4; cb_[k] = -2.f * p5;
    rc[k] = fmaf(p3, p3, fmaf(p4, p4, p5 * p5));
    bD[k] = 3.4e38f; bC[k] = 3.4e38f;
  }
  __syncthreads();                    // cmin init visible

  const float* cbase = preds + ((size_t)b * N + colBase) * 6;
#pragma unroll 2
  for (int j = 0; j < cpc / 16; j++){
    const int c0 = j * 16 + ci * 2;   // local col pair (c0 even -> A 16B-aligned)
    const float* qp = cbase + (size_t)c0 * 6;
    const float4 qa  = *(const float4*)qp;        // Ax,Ay,Az,Acr
    const float2 qb  = *(const float2*)(qp + 4);  // Acg,Acb
    const float2 r0  = *(const float2*)(qp + 6);  // Bx,By
    const float2 r1  = *(const float2*)(qp + 8);  // Bz,Bcr
    const float2 r2  = *(const float2*)(qp + 10); // Bcg,Bcb
    const float ryA = fmaf(qa.x, qa.x, fmaf(qa.y, qa.y, qa.z * qa.z));
    const float rcA = fmaf(qa.w, qa.w, fmaf(qb.x, qb.x, qb.y * qb.y));
    const float ryB = fmaf(r0.x, r0.x, fmaf(r0.y, r0.y, r1.x * r1.x));
    const float rcB = fmaf(r1.y, r1.y, fmaf(r2.x, r2.x, r2.y * r2.y));
    const u32 gA = (u32)(colBase + c0), gB = gA + 1;
    float cpA = 3.4e38f, cpB = 3.4e38f, ccA = 3.4e38f, ccB = 3.4e38f;
#pragma unroll
    for (int k = 0; k < KR; k++){
      float dA = fmaf(az[k], qa.z, fmaf(ay[k], qa.y, fmaf(ax[k], qa.x, ryA + rx[k])));
      float dB = fmaf(az[k], r1.x, fmaf(ay[k], r0.y, fmaf(ax[k], r0.x, ryB + rx[k])));
      float pkA = __uint_as_float((__float_as_uint(dA) & ~IDXM) | gA);
      float pkB = __uint_as_float((__float_as_uint(dB) & ~IDXM) | gB);
      bD[k] = fminf(fminf(pkA, pkB), bD[k]);      // v_min3, ties -> lower idx
      cpA = fminf(cpA, dA); cpB = fminf(cpB, dB);
      float eA = fmaf(cb_[k], qb.y, fmaf(cg_[k], qb.x, fmaf(cr[k], qa.w, rcA + rc[k])));
      float eB = fmaf(cb_[k], r2.y, fmaf(cg_[k], r2.x, fmaf(cr[k], r1.y, rcB + rc[k])));
      bC[k] = fminf(fminf(eA, eB), bC[k]);
      ccA = fminf(ccA, eA); ccB = fminf(ccB, eB);
    }
#pragma unroll
    for (int m = 1; m < 8; m <<= 1){               // reduce over ri lanes
      cpA = fminf(cpA, __shfl_xor(cpA, m, 64));
      cpB = fminf(cpB, __shfl_xor(cpB, m, 64));
      ccA = fminf(ccA, __shfl_xor(ccA, m, 64));
      ccB = fminf(ccB, __shfl_xor(ccB, m, 64));
    }
    if (ri == 0){                                  // 8 lanes, distinct addrs
      atomicMin(&cminP[c0],     __float_as_uint(cpA));
      atomicMin(&cminP[c0 + 1], __float_as_uint(cpB));
      atomicMin(&cminC[c0],     __float_as_uint(ccA));
      atomicMin(&cminC[c0 + 1], __float_as_uint(ccB));
    }
  }

  // row-min merge across ci lanes, commit (uint order == float order, d>=0)
#pragma unroll
  for (int k = 0; k < KR; k++){
    float d = bD[k], c = bC[k];
#pragma unroll
    for (int m = 8; m < 64; m <<= 1){
      d = fminf(d, __shfl_xor(d, m, 64));
      c = fminf(c, __shfl_xor(c, m, 64));
    }
    if (ci == 0){
      size_t g = (size_t)b * N + rowBase + k;
      atomicMin(&packS2F[g], __float_as_uint(d));
      atomicMin(&colMin2[g], __float_as_uint(c));
    }
  }
  // col-min flush
  __syncthreads();
  for (int i = t; i < cpc; i += TPB){
    size_t g = (size_t)b * N + colBase + i;
    atomicMin(&distF2S[g], cminP[i]);
    atomicMin(&colMin1[g], cminC[i]);
  }
}

// acc: [0]=edge_len, [1..6]=Sn[b][c], [7..12]=Se[b][c], [13]=cos, [14]=min sum,
//      [15]=ctrEdge, [16]=ctrFin. 256 blocks -> co-resident; ctrEdge spin is
// edge-blocks-waiting-on-edge-blocks only (deadlock-free, worked in R7).
__global__ void __launch_bounds__(TPB) finish_kernel(
    const float* __restrict__ preds, const float* __restrict__ normals,
    const int* __restrict__ edges,
    u32* __restrict__ packS2F, u32* __restrict__ distF2S,
    u32* __restrict__ colMin2, u32* __restrict__ colMin1,
    float* __restrict__ acc, float* __restrict__ out,
    int N, int E, int nRowBlk, int nEdgeBlk)
{
  __shared__ float rbuf[4];
  __shared__ float buf7[7][4];
  __shared__ float chn[3];

  u32* ctrEdge = (u32*)(acc + 15);
  u32* ctrFin  = (u32*)(acc + 16);
  const int x = (int)blockIdx.x;
  const int t = threadIdx.x;
  const int nTot = nRowBlk + nEdgeBlk;

  if (x < nRowBlk){
    int row = x * TPB + t;                    // BNtot == nRowBlk*TPB
    float invN = 1.f / (float)N;
    float s2f = __uint_as_float(packS2F[row] & ~IDXM);
    float s = 3000.f * invN * __uint_as_float(distF2S[row])
            + 1650.f * invN * s2f
            + __uint_as_float(colMin1[row]) + __uint_as_float(colMin2[row]);
    s = waveReduceSum(s);
    if ((t & 63) == 0) rbuf[t >> 6] = s;
    __syncthreads();
    if (t == 0){
      atomicAdd(&acc[14], rbuf[0] + rbuf[1] + rbuf[2] + rbuf[3]);
      __threadfence();
      u32 old = atomicAdd(ctrFin, 1u);
      if (old == (u32)(nTot - 1)){
        float a0 = aload_f32(&acc[0]), a13 = aload_f32(&acc[13]), a14 = aload_f32(&acc[14]);
        out[0] = a14 + a0 * (300.f / (float)E) + a13 * (0.5f / (float)E);
      }
    }
    return;
  }

  // ---- edge blocks ----
  int gid = (x - nRowBlk) * TPB + t;
  int b = gid / E, e = gid - b * E;           // E%TPB==0 -> block-uniform b
  int e0 = edges[2 * e], e1 = edges[2 * e + 1];
  const float* p0 = preds + ((size_t)b * N + e0) * 6;
  const float* p1 = preds + ((size_t)b * N + e1) * 6;
  float ex = p0[0] - p1[0], ey = p0[1] - p1[1], ez = p0[2] - p1[2];
  u32 idx = packS2F[(size_t)b * N + e0] & IDXM;
  const float* nr = normals + ((size_t)b * N + idx) * 3;
  float n0 = nr[0], n1 = nr[1], n2 = nr[2];
  float t0 = truncf(ex), t1 = truncf(ey), t2 = truncf(ez);
  {
    float v[7] = { fabsf(ex) + fabsf(ey) + fabsf(ez),
                   n0 * n0, n1 * n1, n2 * n2, t0 * t0, t1 * t1, t2 * t2 };
    int lane = t & 63, w = t >> 6;
#pragma unroll
    for (int q = 0; q < 7; q++){
      float s = waveReduceSum(v[q]);
      if (lane == 0) buf7[q][w] = s;
    }
    __syncthreads();
    if (t < 7){
      float s = buf7[t][0] + buf7[t][1] + buf7[t][2] + buf7[t][3];
      int off = (t == 0) ? 0 : ((t < 4) ? (1 + b * 3 + t - 1) : (7 + b * 3 + t - 4));
      atomicAdd(&acc[off], s);
    }
    __syncthreads();
    if (t == 0){ __threadfence(); atomicAdd(ctrEdge, 1u); }
  }
  if (t == 0){
    while (aload_u32(ctrEdge) < (u32)nEdgeBlk) __builtin_amdgcn_s_sleep(2);
    // _unit_axis1 normalizes over the E axis: per (b,channel) norms
#pragma unroll
    for (int c = 0; c < 3; c++){
      float Sn = aload_f32(&acc[1 + b * 3 + c]);
      float Se = aload_f32(&acc[7 + b * 3 + c]);
      chn[c] = 1.f / (fmaxf(sqrtf(Sn), 1e-12f) * fmaxf(sqrtf(Se), 1e-12f));
    }
  }
  __syncthreads();
  float cosv = fabsf(n0 * t0 * chn[0] + n1 * t1 * chn[1] + n2 * t2 * chn[2]);
  cosv = waveReduceSum(cosv);
  if ((t & 63) == 0) rbuf[t >> 6] = cosv;
  __syncthreads();
  if (t == 0){
    atomicAdd(&acc[13], rbuf[0] + rbuf[1] + rbuf[2] + rbuf[3]);
    __threadfence();
    u32 old = atomicAdd(ctrFin, 1u);
    if (old == (u32)(nTot - 1)){
      float a0 = aload_f32(&acc[0]), a13 = aload_f32(&acc[13]), a14 = aload_f32(&acc[14]);
      out[0] = a14 + a0 * (300.f / (float)E) + a13 * (0.5f / (float)E);
    }
  }
}

extern "C" void kernel_launch(void* const* d_in, const int* in_sizes, int n_in,
                              void* d_out, int out_size, void* d_ws, size_t ws_size,
                              hipStream_t stream)
{
  const float* gts     = (const float*)d_in[0];
  const float* preds   = (const float*)d_in[1];
  const float* normals = (const float*)d_in[2];
  const int*   edges   = (const int*)d_in[3];

  const int B = 2;
  const int BNtot = in_sizes[2] / 3;   // B*N from gts_normals
  const int N = BNtot / B;
  const int E = in_sizes[3] / 2;

  char* ws = (char*)d_ws;
  float* acc   = (float*)ws;                                  // 32 f32 (128 B)
  u32* packS2F = (u32*)(ws + 128);                            // BN u32 (dist|idx13)
  u32* distF2S = (u32*)(ws + 128 + (size_t)BNtot * 4);        // BN u32
  u32* colMin2 = (u32*)(ws + 128 + (size_t)BNtot * 8);        // BN u32
  u32* colMin1 = (u32*)(ws + 128 + (size_t)BNtot * 12);       // BN u32

  hipMemsetAsync(ws, 0, 128, stream);                         // acc + counters
  hipMemsetAsync(ws + 128, 0xFF, (size_t)BNtot * 16, stream); // +inf sentinels

  int cpc = N / CS;                                    // 512
  dim3 gp((N / ROWS_PB) * CS, B);                      // 512 x 2 = 1024 blocks
  pass_kernel<<<gp, TPB, 0, stream>>>(gts, preds, packS2F, distF2S,
                                      colMin2, colMin1, N, cpc);

  int nRowBlk = BNtot / TPB;                           // 64
  int nEdgeBlk = (B * E) / TPB;                        // 192
  finish_kernel<<<nRowBlk + nEdgeBlk, TPB, 0, stream>>>(
      preds, normals, edges, packS2F, distF2S, colMin2, colMin1,
      acc, (float*)d_out, N, E, nRowBlk, nEdgeBlk);
}

// Round 9
// 147.682 us; speedup vs baseline: 1.0384x; 1.0384x over previous
//
#include <hip/hip_runtime.h>
#include <stdint.h>

#define TPB 256
#define CS 16
#define IDXM 0x1FFFu

typedef unsigned long long u64;
typedef unsigned int u32;

__device__ __forceinline__ float waveReduceSum(float v){
#pragma unroll
  for (int o = 32; o > 0; o >>= 1) v += __shfl_down(v, o, 64);
  return v;
}

__device__ __forceinline__ u32 aload_u32(u32* p){
  return __hip_atomic_load(p, __ATOMIC_ACQUIRE, __HIP_MEMORY_SCOPE_AGENT);
}
__device__ __forceinline__ float aload_f32(float* p){
  return __hip_atomic_load(p, __ATOMIC_ACQUIRE, __HIP_MEMORY_SCOPE_AGENT);
}

// Fused single-compute pass, LDS-staged (R8's fusion + R7's memory structure).
// rows = gts (256/block, 8/lane via ri=lane&7), cols = preds (cpc=512/block,
// staged 256 at a time as float4 {x,y,z,ry} / {r,g,b,rc}). Lane grid 8x8:
// ci=lane>>3 picks a col pair per j-step. Each (row,col) pt+color distance is
// computed ONCE and feeds BOTH the row-min (s2f + argmin via 13-bit mantissa
// pack -> v_min3; R8 validated absmax 0.0) and the col-min (f2s; 3x
// shfl_xor over the 8 ri-lanes then LDS atomicMin from ri==0 lanes).
// LDS slot swizzle s(c) = (c&~7)|((c+(c>>3))&7): the 8 ci-lanes' float4
// reads land on 8 distinct bank quads -> conflict-free ds_read_b128.
__global__ void __launch_bounds__(TPB) pass_kernel(
    const float* __restrict__ gts, const float* __restrict__ preds,
    u32* __restrict__ packS2F, u32* __restrict__ distF2S,
    u32* __restrict__ colMin2, u32* __restrict__ colMin1,
    int N, int cpc)
{
  __shared__ float4 ptsT[256];
  __shared__ float4 colT[256];
  __shared__ u32 cminP[512];
  __shared__ u32 cminC[512];

  const int b = blockIdx.y;
  const int rb = blockIdx.x / CS;
  const int chunk = blockIdx.x - rb * CS;
  const int t = threadIdx.x;
  const int lane = t & 63, w = t >> 6;
  const int ri = lane & 7, ci = lane >> 3;
  const int rowBase = rb * 256 + w * 64 + ri * 8;
  const int colBase = chunk * cpc;

  for (int i = t; i < cpc; i += TPB){ cminP[i] = ~0u; cminC[i] = ~0u; }

  float ax[8], ay[8], az[8], rx[8];
  float cr[8], cg_[8], cb_[8], rc[8];
  float bD[8], bC[8];
#pragma unroll
  for (int k = 0; k < 8; k++){
    const float* p = gts + ((size_t)b * N + rowBase + k) * 6;
    float p0 = p[0], p1 = p[1], p2 = p[2], p3 = p[3], p4 = p[4], p5 = p[5];
    ax[k] = -2.f * p0; ay[k] = -2.f * p1; az[k] = -2.f * p2;
    rx[k] = fmaf(p0, p0, fmaf(p1, p1, p2 * p2));
    cr[k] = -2.f * p3; cg_[k] = -2.f * p4; cb_[k] = -2.f * p5;
    rc[k] = fmaf(p3, p3, fmaf(p4, p4, p5 * p5));
    bD[k] = 3.4e38f; bC[k] = 3.4e38f;
  }

  for (int tb = 0; tb < cpc; tb += 256){
    __syncthreads();                    // prior tile's reads (and cmin init) done
    {
      const float* p = preds + ((size_t)b * N + colBase + tb + t) * 6;
      float2 q0 = *(const float2*)p;        // x,y  (24B stride -> 8B aligned)
      float2 q1 = *(const float2*)(p + 2);  // z,r
      float2 q2 = *(const float2*)(p + 4);  // g,b
      int s = (t & ~7) | ((t + (t >> 3)) & 7);
      ptsT[s] = make_float4(q0.x, q0.y, q1.x,
                            fmaf(q0.x, q0.x, fmaf(q0.y, q0.y, q1.x * q1.x)));
      colT[s] = make_float4(q1.y, q2.x, q2.y,
                            fmaf(q1.y, q1.y, fmaf(q2.x, q2.x, q2.y * q2.y)));
    }
    __syncthreads();
#pragma unroll 2
    for (int j = 0; j < 16; j++){
      const int c0 = j * 16 + ci * 2;
      const int sA = (c0 & ~7) | ((c0 + (c0 >> 3)) & 7);
      const int sB = (sA & ~7) | ((sA + 1) & 7);
      const float4 pA = ptsT[sA], pB = ptsT[sB];
      const float4 cA = colT[sA], cB = colT[sB];
      const u32 gA = (u32)(colBase + tb + c0), gB = gA + 1;
      float cpA = 3.4e38f, cpB = 3.4e38f, ccA = 3.4e38f, ccB = 3.4e38f;
#pragma unroll
      for (int k = 0; k < 8; k++){
        float dA = fmaf(ax[k], pA.x, fmaf(ay[k], pA.y, fmaf(az[k], pA.z, pA.w + rx[k])));
        float dB = fmaf(ax[k], pB.x, fmaf(ay[k], pB.y, fmaf(az[k], pB.z, pB.w + rx[k])));
        float pkA = __uint_as_float((__float_as_uint(dA) & ~IDXM) | gA);
        float pkB = __uint_as_float((__float_as_uint(dB) & ~IDXM) | gB);
        bD[k] = fminf(fminf(pkA, pkB), bD[k]);      // v_min3, ties -> lower idx
        cpA = fminf(cpA, pkA); cpB = fminf(cpB, pkB);
        float eA = fmaf(cr[k], cA.x, fmaf(cg_[k], cA.y, fmaf(cb_[k], cA.z, cA.w + rc[k])));
        float eB = fmaf(cr[k], cB.x, fmaf(cg_[k], cB.y, fmaf(cb_[k], cB.z, cB.w + rc[k])));
        bC[k] = fminf(fminf(eA, eB), bC[k]);
        ccA = fminf(ccA, eA); ccB = fminf(ccB, eB);
      }
#pragma unroll
      for (int m = 1; m < 8; m <<= 1){               // reduce over the 8 ri-lanes
        cpA = fminf(cpA, __shfl_xor(cpA, m, 64));
        cpB = fminf(cpB, __shfl_xor(cpB, m, 64));
        ccA = fminf(ccA, __shfl_xor(ccA, m, 64));
        ccB = fminf(ccB, __shfl_xor(ccB, m, 64));
      }
      if (ri == 0){                                  // 8 lanes, distinct addrs
        int cc = tb + c0;
        atomicMin(&cminP[cc],     __float_as_uint(cpA));
        atomicMin(&cminP[cc + 1], __float_as_uint(cpB));
        atomicMin(&cminC[cc],     __float_as_uint(ccA));
        atomicMin(&cminC[cc + 1], __float_as_uint(ccB));
      }
    }
  }

  // row-min commit: reduce over the 8 ci-lanes, then global atomicMin
#pragma unroll
  for (int k = 0; k < 8; k++){
    float d = bD[k], c = bC[k];
#pragma unroll
    for (int m = 8; m < 64; m <<= 1){
      d = fminf(d, __shfl_xor(d, m, 64));
      c = fminf(c, __shfl_xor(c, m, 64));
    }
    if (ci == 0){
      size_t g = (size_t)b * N + rowBase + k;
      atomicMin(&packS2F[g], __float_as_uint(d));
      atomicMin(&colMin2[g], __float_as_uint(c));
    }
  }
  // col-min flush
  __syncthreads();
  for (int i = t; i < cpc; i += TPB){
    size_t g = (size_t)b * N + colBase + i;
    atomicMin(&distF2S[g], cminP[i]);
    atomicMin(&colMin1[g], cminC[i]);
  }
}

// acc: [0]=edge_len, [1..6]=Sn[b][c], [7..12]=Se[b][c], [13]=cos, [14]=min sum,
//      [15]=ctrEdge, [16]=ctrFin. 256 blocks -> co-resident; ctrEdge spin is
// edge-blocks-waiting-on-edge-blocks only (proven in R7/R8).
__global__ void __launch_bounds__(TPB) finish_kernel(
    const float* __restrict__ preds, const float* __restrict__ normals,
    const int* __restrict__ edges,
    u32* __restrict__ packS2F, u32* __restrict__ distF2S,
    u32* __restrict__ colMin2, u32* __restrict__ colMin1,
    float* __restrict__ acc, float* __restrict__ out,
    int N, int E, int nRowBlk, int nEdgeBlk)
{
  __shared__ float rbuf[4];
  __shared__ float buf7[7][4];
  __shared__ float chn[3];

  u32* ctrEdge = (u32*)(acc + 15);
  u32* ctrFin  = (u32*)(acc + 16);
  const int x = (int)blockIdx.x;
  const int t = threadIdx.x;
  const int nTot = nRowBlk + nEdgeBlk;

  if (x < nRowBlk){
    int row = x * TPB + t;                    // BNtot == nRowBlk*TPB
    float invN = 1.f / (float)N;
    float s2f = __uint_as_float(packS2F[row] & ~IDXM);
    float s = 3000.f * invN * __uint_as_float(distF2S[row])
            + 1650.f * invN * s2f
            + __uint_as_float(colMin1[row]) + __uint_as_float(colMin2[row]);
    s = waveReduceSum(s);
    if ((t & 63) == 0) rbuf[t >> 6] = s;
    __syncthreads();
    if (t == 0){
      atomicAdd(&acc[14], rbuf[0] + rbuf[1] + rbuf[2] + rbuf[3]);
      __threadfence();
      u32 old = atomicAdd(ctrFin, 1u);
      if (old == (u32)(nTot - 1)){
        float a0 = aload_f32(&acc[0]), a13 = aload_f32(&acc[13]), a14 = aload_f32(&acc[14]);
        out[0] = a14 + a0 * (300.f / (float)E) + a13 * (0.5f / (float)E);
      }
    }
    return;
  }

  // ---- edge blocks ----
  int gid = (x - nRowBlk) * TPB + t;
  int b = gid / E, e = gid - b * E;           // E%TPB==0 -> block-uniform b
  int e0 = edges[2 * e], e1 = edges[2 * e + 1];
  const float* p0 = preds + ((size_t)b * N + e0) * 6;
  const float* p1 = preds + ((size_t)b * N + e1) * 6;
  float ex = p0[0] - p1[0], ey = p0[1] - p1[1], ez = p0[2] - p1[2];
  u32 idx = packS2F[(size_t)b * N + e0] & IDXM;
  const float* nr = normals + ((size_t)b * N + idx) * 3;
  float n0 = nr[0], n1 = nr[1], n2 = nr[2];
  float t0 = truncf(ex), t1 = truncf(ey), t2 = truncf(ez);
  {
    float v[7] = { fabsf(ex) + fabsf(ey) + fabsf(ez),
                   n0 * n0, n1 * n1, n2 * n2, t0 * t0, t1 * t1, t2 * t2 };
    int lane = t & 63, w = t >> 6;
#pragma unroll
    for (int q = 0; q < 7; q++){
      float s = waveReduceSum(v[q]);
      if (lane == 0) buf7[q][w] = s;
    }
    __syncthreads();
    if (t < 7){
      float s = buf7[t][0] + buf7[t][1] + buf7[t][2] + buf7[t][3];
      int off = (t == 0) ? 0 : ((t < 4) ? (1 + b * 3 + t - 1) : (7 + b * 3 + t - 4));
      atomicAdd(&acc[off], s);
    }
    __syncthreads();
    if (t == 0){ __threadfence(); atomicAdd(ctrEdge, 1u); }
  }
  if (t == 0){
    while (aload_u32(ctrEdge) < (u32)nEdgeBlk) __builtin_amdgcn_s_sleep(2);
    // _unit_axis1 normalizes over the E axis: per (b,channel) norms
#pragma unroll
    for (int c = 0; c < 3; c++){
      float Sn = aload_f32(&acc[1 + b * 3 + c]);
      float Se = aload_f32(&acc[7 + b * 3 + c]);
      chn[c] = 1.f / (fmaxf(sqrtf(Sn), 1e-12f) * fmaxf(sqrtf(Se), 1e-12f));
    }
  }
  __syncthreads();
  float cosv = fabsf(n0 * t0 * chn[0] + n1 * t1 * chn[1] + n2 * t2 * chn[2]);
  cosv = waveReduceSum(cosv);
  if ((t & 63) == 0) rbuf[t >> 6] = cosv;
  __syncthreads();
  if (t == 0){
    atomicAdd(&acc[13], rbuf[0] + rbuf[1] + rbuf[2] + rbuf[3]);
    __threadfence();
    u32 old = atomicAdd(ctrFin, 1u);
    if (old == (u32)(nTot - 1)){
      float a0 = aload_f32(&acc[0]), a13 = aload_f32(&acc[13]), a14 = aload_f32(&acc[14]);
      out[0] = a14 + a0 * (300.f / (float)E) + a13 * (0.5f / (float)E);
    }
  }
}

extern "C" void kernel_launch(void* const* d_in, const int* in_sizes, int n_in,
                              void* d_out, int out_size, void* d_ws, size_t ws_size,
                              hipStream_t stream)
{
  const float* gts     = (const float*)d_in[0];
  const float* preds   = (const float*)d_in[1];
  const float* normals = (const float*)d_in[2];
  const int*   edges   = (const int*)d_in[3];

  const int B = 2;
  const int BNtot = in_sizes[2] / 3;   // B*N from gts_normals
  const int N = BNtot / B;
  const int E = in_sizes[3] / 2;

  char* ws = (char*)d_ws;
  float* acc   = (float*)ws;                                  // 32 f32 (128 B)
  u32* packS2F = (u32*)(ws + 128);                            // BN u32 (dist|idx13)
  u32* distF2S = (u32*)(ws + 128 + (size_t)BNtot * 4);        // BN u32
  u32* colMin2 = (u32*)(ws + 128 + (size_t)BNtot * 8);        // BN u32
  u32* colMin1 = (u32*)(ws + 128 + (size_t)BNtot * 12);       // BN u32

  hipMemsetAsync(ws, 0, 128, stream);                         // acc + counters
  hipMemsetAsync(ws + 128, 0xFF, (size_t)BNtot * 16, stream); // +inf sentinels

  int cpc = N / CS;                                    // 512
  dim3 gp((N / 256) * CS, B);                          // 512 x 2 = 1024 blocks
  pass_kernel<<<gp, TPB, 0, stream>>>(gts, preds, packS2F, distF2S,
                                      colMin2, colMin1, N, cpc);

  int nRowBlk = BNtot / TPB;                           // 64
  int nEdgeBlk = (B * E) / TPB;                        // 192
  finish_kernel<<<nRowBlk + nEdgeBlk, TPB, 0, stream>>>(
      preds, normals, edges, packS2F, distF2S, colMin2, colMin1,
      acc, (float*)d_out, N, E, nRowBlk, nEdgeBlk);
}